// Round 3
// baseline (321.831 us; speedup 1.0000x reference)
//
#include <hip/hip_runtime.h>

typedef unsigned short u16;
typedef __attribute__((ext_vector_type(8))) __bf16 bf16x8;
typedef __attribute__((ext_vector_type(4))) float f32x4;

#define B_SZ   2
#define S_LEN  2048
#define E_DIM  1024
#define NHEAD  16
#define HD     64
#define KDIM   1024
#define NOUT   4096   // q|k|v|g concatenated

__device__ __forceinline__ float bf2f(u16 u){
  union { unsigned int i; float f; } c; c.i = ((unsigned int)u) << 16; return c.f;
}
__device__ __forceinline__ u16 f2bf(float f){
  union { float f; unsigned int i; } c; c.f = f;
  return (u16)((c.i + 0x7FFFu + ((c.i >> 16) & 1u)) >> 16);
}
__device__ __forceinline__ u16 f2bf_fast(float f){  // round-half-up, 2 ops
  union { float f; unsigned int i; } c; c.f = f;
  return (u16)((c.i + 0x8000u) >> 16);
}
__device__ __forceinline__ void gl2lds16(const void* g, void* l){
  __builtin_amdgcn_global_load_lds((const __attribute__((address_space(1))) void*)g,
                                   (__attribute__((address_space(3))) void*)l, 16, 0, 0);
}

// ---------------- cast x: fp32 -> bf16, tile-swizzled (cb ^= row&7 within 64-col tiles) ----------------
__global__ __launch_bounds__(256) void castx_kernel(const float* __restrict__ x, u16* __restrict__ xb){
  size_t flat = ((size_t)blockIdx.x * 256 + threadIdx.x) * 16;
  int m7 = (int)((flat >> 10) & 7);
  int cb = (int)((flat >> 3) & 7);         // even (16-aligned)
  size_t tile = flat & ~(size_t)63;
  float f[16];
  #pragma unroll
  for (int c = 0; c < 4; c++) *(float4*)&f[c * 4] = *(const float4*)&x[flat + c * 4];
  u16 o[16];
  #pragma unroll
  for (int i = 0; i < 16; i++) o[i] = f2bf(f[i]);
  *(uint4*)&xb[tile + ((cb ^ m7) * 8)]       = *(uint4*)&o[0];
  *(uint4*)&xb[tile + (((cb + 1) ^ m7) * 8)] = *(uint4*)&o[8];
}

// ---------------- W transpose + cast: WT[z*1024 + n][k] = bf16(W_z[k][n]), swizzled ----------------
__global__ __launch_bounds__(256) void wtrans_kernel(const float* __restrict__ Wq, const float* __restrict__ Wk,
                                                     const float* __restrict__ Wv, const float* __restrict__ Wg,
                                                     u16* __restrict__ WT){
  const float* Ws[4] = {Wq, Wk, Wv, Wg};
  const float* W = Ws[blockIdx.z];
  int n0 = blockIdx.x * 64, k0 = blockIdx.y * 64;
  __shared__ u16 tile[64][66];
  int t = threadIdx.x;
  int r = t >> 2, cg = (t & 3) * 16;
  const float* src = W + (size_t)(k0 + r) * E_DIM + n0 + cg;
  float f[16];
  #pragma unroll
  for (int c = 0; c < 4; c++) *(float4*)&f[c * 4] = *(const float4*)&src[c * 4];
  #pragma unroll
  for (int i = 0; i < 16; i++) tile[r][cg + i] = f2bf(f[i]);
  __syncthreads();
  u16 ov[16];
  #pragma unroll
  for (int i = 0; i < 16; i++) ov[i] = tile[cg + i][r];    // (n=n0+r, k=k0+cg+i)
  int n7 = r & 7, cb = cg >> 3;
  u16* dst = WT + (size_t)(blockIdx.z * E_DIM + n0 + r) * KDIM + k0;
  *(uint4*)&dst[(cb ^ n7) * 8]       = *(uint4*)&ov[0];
  *(uint4*)&dst[((cb + 1) ^ n7) * 8] = *(uint4*)&ov[8];
}

// ---------------- fused QKVG GEMM: C[4096 tok][4096] = xb @ [Wq|Wk|Wv|Wg] (bf16, swizzled LDS) ----------------
__global__ __launch_bounds__(256) void gemm_kernel(const u16* __restrict__ A, const u16* __restrict__ Bt,
                                                   u16* __restrict__ C){
  __shared__ __align__(16) u16 As[128 * 64];
  __shared__ __align__(16) u16 Bs[128 * 64];
  int m0 = blockIdx.y * 128, n0 = blockIdx.x * 128;
  int t = threadIdx.x;
  int wave = t >> 6, lane = t & 63;
  int l15 = lane & 15, quad = lane >> 4, h8 = lane & 7;
  int r0 = (wave & 1) * 64, c0 = (wave >> 1) * 64;
  f32x4 acc[4][4];
  #pragma unroll
  for (int i = 0; i < 4; i++)
    #pragma unroll
    for (int j = 0; j < 4; j++) acc[i][j] = (f32x4){0.f, 0.f, 0.f, 0.f};

  for (int k0 = 0; k0 < KDIM; k0 += 64){
    __syncthreads();
    #pragma unroll
    for (int c = 0; c < 4; c++){
      int L = c * 256 + t;
      gl2lds16(A + (size_t)(m0 + (L >> 3)) * KDIM + k0 + (L & 7) * 8, &As[L * 8]);
    }
    #pragma unroll
    for (int c = 0; c < 4; c++){
      int L = c * 256 + t;
      gl2lds16(Bt + (size_t)(n0 + (L >> 3)) * KDIM + k0 + (L & 7) * 8, &Bs[L * 8]);
    }
    __syncthreads();
    #pragma unroll
    for (int kk = 0; kk < 2; kk++){
      bf16x8 a[4], b[4];
      int pcb = ((kk * 4) ^ (h8 & 4)) | ((quad ^ h8) & 3);  // (kk*4+quad) ^ h8
      #pragma unroll
      for (int i = 0; i < 4; i++) a[i] = *(const bf16x8*)&As[(r0 + i * 16 + l15) * 64 + ((kk * 4 + quad) ^ h8) * 8];
      #pragma unroll
      for (int j = 0; j < 4; j++) b[j] = *(const bf16x8*)&Bs[(c0 + j * 16 + l15) * 64 + ((kk * 4 + quad) ^ h8) * 8];
      (void)pcb;
      #pragma unroll
      for (int i = 0; i < 4; i++)
        #pragma unroll
        for (int j = 0; j < 4; j++)
          acc[i][j] = __builtin_amdgcn_mfma_f32_16x16x32_bf16(a[i], b[j], acc[i][j], 0, 0, 0);
    }
  }
  #pragma unroll
  for (int i = 0; i < 4; i++){
    int row = m0 + r0 + i * 16 + quad * 4;
    #pragma unroll
    for (int j = 0; j < 4; j++){
      int col = n0 + c0 + j * 16 + l15;
      #pragma unroll
      for (int r = 0; r < 4; r++)
        C[(size_t)(row + r) * NOUT + col] = f2bf(acc[i][j][r]);
    }
  }
}

// ---------------- rotary shift + head-major transpose ----------------
// qr: (B*H, S, D) PLAIN ; kr: (B*H, S, D) swizzled ; vt: (B*H, D, S) swizzled ; k folds E^-0.5.
__global__ __launch_bounds__(256) void shift_kernel(const u16* __restrict__ qkvg,
                                                    u16* __restrict__ qr, u16* __restrict__ kr,
                                                    u16* __restrict__ vt){
  int sb = blockIdx.x, bh = blockIdx.y;
  int s0 = sb * 64;
  int t = threadIdx.x;
  int sl = t >> 2, dg = (t & 3) * 16;
  int s = s0 + sl;
  int h = bh & 15;
  size_t token = (size_t)(bh >> 4) * S_LEN + s;
  size_t base = token * NOUT + h * HD + dg;
  u16 qv[16], kv[16], vv[16];
  *(uint4*)&qv[0] = *(const uint4*)&qkvg[base];
  *(uint4*)&qv[8] = *(const uint4*)&qkvg[base + 8];
  *(uint4*)&kv[0] = *(const uint4*)&qkvg[base + 1024];
  *(uint4*)&kv[8] = *(const uint4*)&qkvg[base + 1024 + 8];
  *(uint4*)&vv[0] = *(const uint4*)&qkvg[base + 2048];
  *(uint4*)&vv[8] = *(const uint4*)&qkvg[base + 2048 + 8];
  u16 qo[16], ko[16];
  #pragma unroll
  for (int i = 0; i < 8; i++){
    int dd = dg + 2 * i;
    float a = exp2f(-(float)(dd >> 1) * (13.287712379549449f / 31.0f));
    float ang = (float)s * a;
    float sn = sinf(ang), cs = cosf(ang);
    float qe = bf2f(qv[2 * i]), qd = bf2f(qv[2 * i + 1]);
    qo[2 * i]     = f2bf(qe * cs - qd * sn);
    qo[2 * i + 1] = f2bf(qd * cs + qe * sn);
    float ke = bf2f(kv[2 * i]) * 0.03125f, kd = bf2f(kv[2 * i + 1]) * 0.03125f;
    ko[2 * i]     = f2bf(ke * cs - kd * sn);
    ko[2 * i + 1] = f2bf(kd * cs + ke * sn);
  }
  size_t dsto = ((size_t)bh * S_LEN + s) * HD;
  *(uint4*)&qr[dsto + dg]     = *(uint4*)&qo[0];
  *(uint4*)&qr[dsto + dg + 8] = *(uint4*)&qo[8];
  int s7 = s & 7, cbk = dg >> 3;
  *(uint4*)&kr[dsto + ((cbk ^ s7) * 8)]       = *(uint4*)&ko[0];
  *(uint4*)&kr[dsto + (((cbk + 1) ^ s7) * 8)] = *(uint4*)&ko[8];
  // v transpose via LDS
  __shared__ u16 vs[64][66];
  #pragma unroll
  for (int i = 0; i < 16; i++) vs[sl][dg + i] = vv[i];
  __syncthreads();
  int d = t >> 2, jg = (t & 3) * 16;
  u16 ov[16];
  #pragma unroll
  for (int i = 0; i < 16; i++) ov[i] = vs[jg + i][d];   // (d, s0+jg+i)
  int d7 = d & 7, cbv = jg >> 3;
  size_t vrow = ((size_t)bh * HD + d) * S_LEN + s0;
  *(uint4*)&vt[vrow + ((cbv ^ d7) * 8)]       = *(uint4*)&ov[0];
  *(uint4*)&vt[vrow + (((cbv + 1) ^ d7) * 8)] = *(uint4*)&ov[8];
}

// ---------------- fused retention v2: 128-row Q tile, separable mask, swizzled K/V ----------------
__global__ __launch_bounds__(256, 4) void retention_kernel(const u16* __restrict__ qr, const u16* __restrict__ kr,
                                                           const u16* __restrict__ vt, const u16* __restrict__ qkvg,
                                                           float* __restrict__ out){
  int bh = blockIdx.x;
  int qb = 15 - (int)blockIdx.y;          // big-first dispatch
  int b = bh >> 4, h = bh & 15;
  int q0 = qb * 128;
  __shared__ __align__(16) u16 Ks[64 * 64];
  __shared__ __align__(16) u16 Vs[64 * 64];
  __shared__ __align__(16) u16 Ps[128 * 72];   // stride 72: bank-floor reads, ~2-way writes
  int t = threadIdx.x, wave = t >> 6, lane = t & 63;
  int l15 = lane & 15, quad = lane >> 4, h8 = lane & 7;

  float decay = log1pf(-exp2f(-5.0f - (float)h));   // ln(gamma_h) < 0
  float negd = -decay;
  float estep = __expf(64.0f * decay * -1.0f);      // exp(64*|d|)

  int qsE[2]; int rowbase[2];
  #pragma unroll
  for (int e = 0; e < 2; e++){ rowbase[e] = wave * 32 + e * 16; qsE[e] = q0 + rowbase[e]; }

  // Q fragments direct from global (plain layout)
  bf16x8 aqa[2], aqb[2];
  #pragma unroll
  for (int e = 0; e < 2; e++){
    size_t qrow = ((size_t)bh * S_LEN + qsE[e] + l15) * HD;
    aqa[e] = *(const bf16x8*)&qr[qrow + quad * 8];
    aqb[e] = *(const bf16x8*)&qr[qrow + 32 + quad * 8];
  }

  // hoisted column factor: cf[ct] = exp((j-k0)*|d|), j-k0 = ct*16+l15
  float cf[4];
  #pragma unroll
  for (int ct = 0; ct < 4; ct++) cf[ct] = __expf((float)(ct * 16 + l15) * negd);

  // per-row: qi, rinv
  int qi[2][4]; float rf[2][4];
  float em1d = expm1f(decay);
  float win_f = 18.0f / negd;
  int win_i = (win_f > 2.1e9f) ? 0x7f000000 : (int)win_f;
  int jmin = q0 - win_i;
  int kb_start = jmin > 0 ? (jmin >> 6) : 0;
  int k0s = kb_start * 64;
  #pragma unroll
  for (int e = 0; e < 2; e++)
    #pragma unroll
    for (int r = 0; r < 4; r++){
      qi[e][r] = qsE[e] + quad * 4 + r;
      float rowsum = expm1f((float)(qi[e][r] + 1) * decay) / em1d;
      float rinv = rsqrtf(rowsum);
      rf[e][r] = __expf((float)(qi[e][r] - k0s) * decay) * rinv;
    }

  f32x4 o[2][4];
  #pragma unroll
  for (int e = 0; e < 2; e++)
    #pragma unroll
    for (int dt = 0; dt < 4; dt++) o[e][dt] = (f32x4){0.f, 0.f, 0.f, 0.f};
  float babs[2][4] = {{0.f,0.f,0.f,0.f},{0.f,0.f,0.f,0.f}};

  const u16* krbh = kr + (size_t)bh * S_LEN * HD;
  const u16* vtbh = vt + (size_t)bh * HD * S_LEN;
  int kbend = 2 * qb + 1;

  for (int kb = kb_start; kb <= kbend; kb++){
    int k0 = kb * 64;
    __syncthreads();
    #pragma unroll
    for (int c = 0; c < 2; c++){
      int L = c * 256 + t;
      gl2lds16(krbh + (size_t)(k0) * HD + L * 8, &Ks[L * 8]);
    }
    #pragma unroll
    for (int c = 0; c < 2; c++){
      int L = c * 256 + t;
      gl2lds16(vtbh + (size_t)(L >> 3) * S_LEN + k0 + (L & 7) * 8, &Vs[L * 8]);
    }
    __syncthreads();

    // K b-frags (swizzled rows)
    bf16x8 bk0[4], bk1[4];
    #pragma unroll
    for (int ct = 0; ct < 4; ct++){
      int rw = (ct * 16 + l15) * 64;
      bk0[ct] = *(const bf16x8*)&Ks[rw + ((quad ^ h8) * 8)];
      bk1[ct] = *(const bf16x8*)&Ks[rw + (((quad + 4) ^ h8) * 8)];
    }
    #pragma unroll
    for (int e = 0; e < 2; e++){
      int qs = qsE[e];
      if (k0 <= qs + 15 && k0 + 63 >= qs - win_i){
        f32x4 s4[4];
        #pragma unroll
        for (int ct = 0; ct < 4; ct++){
          f32x4 z = (f32x4){0.f, 0.f, 0.f, 0.f};
          z = __builtin_amdgcn_mfma_f32_16x16x32_bf16(aqa[e], bk0[ct], z, 0, 0, 0);
          z = __builtin_amdgcn_mfma_f32_16x16x32_bf16(aqb[e], bk1[ct], z, 0, 0, 0);
          s4[ct] = z;
        }
        bool diag = (k0 + 64 > qs);
        #pragma unroll
        for (int ct = 0; ct < 4; ct++){
          int j = k0 + ct * 16 + l15;
          #pragma unroll
          for (int r = 0; r < 4; r++){
            float p = s4[ct][r] * (rf[e][r] * cf[ct]);
            if (diag && j > qi[e][r]) p = 0.f;
            babs[e][r] += fabsf(p);
            Ps[(rowbase[e] + quad * 4 + r) * 72 + ct * 16 + l15] = f2bf_fast(p);
          }
        }
      }
    }
    // V b-frags (swizzled rows) + PV
    bf16x8 bv0[4], bv1[4];
    #pragma unroll
    for (int dt = 0; dt < 4; dt++){
      int rw = (dt * 16 + l15) * 64;
      bv0[dt] = *(const bf16x8*)&Vs[rw + ((quad ^ h8) * 8)];
      bv1[dt] = *(const bf16x8*)&Vs[rw + (((quad + 4) ^ h8) * 8)];
    }
    #pragma unroll
    for (int e = 0; e < 2; e++){
      int qs = qsE[e];
      if (k0 <= qs + 15 && k0 + 63 >= qs - win_i){
        bf16x8 ap0 = *(const bf16x8*)&Ps[(rowbase[e] + l15) * 72 + quad * 8];
        bf16x8 ap1 = *(const bf16x8*)&Ps[(rowbase[e] + l15) * 72 + 32 + quad * 8];
        #pragma unroll
        for (int dt = 0; dt < 4; dt++){
          o[e][dt] = __builtin_amdgcn_mfma_f32_16x16x32_bf16(ap0, bv0[dt], o[e][dt], 0, 0, 0);
          o[e][dt] = __builtin_amdgcn_mfma_f32_16x16x32_bf16(ap1, bv1[dt], o[e][dt], 0, 0, 0);
        }
      }
    }
    // advance row factors (k0 += 64 => rf *= exp(64*|d|))
    #pragma unroll
    for (int e = 0; e < 2; e++)
      #pragma unroll
      for (int r = 0; r < 4; r++) rf[e][r] *= estep;
  }

  // ---- epilogue: denom clip, RMS over D, SiLU(g) gate ----
  #pragma unroll
  for (int e = 0; e < 2; e++){
    float dinv[4];
    #pragma unroll
    for (int r = 0; r < 4; r++){
      float v = babs[e][r];
      v += __shfl_xor(v, 1); v += __shfl_xor(v, 2);
      v += __shfl_xor(v, 4); v += __shfl_xor(v, 8);
      dinv[r] = 1.0f / fminf(fmaxf(v, 1.0f), 50000.0f);
    }
    float ssq[4] = {0.f, 0.f, 0.f, 0.f};
    #pragma unroll
    for (int dt = 0; dt < 4; dt++)
      #pragma unroll
      for (int r = 0; r < 4; r++){
        float v = o[e][dt][r] * dinv[r];
        o[e][dt][r] = v;
        ssq[r] += v * v;
      }
    #pragma unroll
    for (int r = 0; r < 4; r++){
      float v = ssq[r];
      v += __shfl_xor(v, 1); v += __shfl_xor(v, 2);
      v += __shfl_xor(v, 4); v += __shfl_xor(v, 8);
      ssq[r] = rsqrtf(v * (1.0f / 64.0f) + 1e-6f);
    }
    #pragma unroll
    for (int r = 0; r < 4; r++){
      int s = qi[e][r];
      size_t gbase = ((size_t)b * S_LEN + s) * NOUT + 3072 + h * HD;
      size_t obase = ((size_t)b * S_LEN + s) * E_DIM + h * HD;
      #pragma unroll
      for (int dt = 0; dt < 4; dt++){
        int d = dt * 16 + l15;
        float gv = bf2f(qkvg[gbase + d]);
        float sg = gv / (1.0f + __expf(-gv));
        out[obase + d] = o[e][dt][r] * ssq[r] * sg;
      }
    }
  }
}

extern "C" void kernel_launch(void* const* d_in, const int* in_sizes, int n_in,
                              void* d_out, int out_size, void* d_ws, size_t ws_size,
                              hipStream_t stream){
  const float* x  = (const float*)d_in[0];
  const float* Wq = (const float*)d_in[1];
  const float* Wk = (const float*)d_in[2];
  const float* Wv = (const float*)d_in[3];
  const float* Wg = (const float*)d_in[4];
  float* out = (float*)d_out;
  char* ws = (char*)d_ws;
  // ws layout: xb->qr overlay [0,8M) | WT->vt overlay [8,16M) | qkvg [16,48M) | kr [48,56M)
  u16* xb   = (u16*)(ws);
  u16* WT   = (u16*)(ws + (8ull  << 20));
  u16* qkvg = (u16*)(ws + (16ull << 20));
  u16* qrp  = (u16*)(ws);
  u16* vtp  = (u16*)(ws + (8ull  << 20));
  u16* krp  = (u16*)(ws + (48ull << 20));

  castx_kernel    <<<dim3(1024),      256, 0, stream>>>(x, xb);
  wtrans_kernel   <<<dim3(16, 16, 4), 256, 0, stream>>>(Wq, Wk, Wv, Wg, WT);
  gemm_kernel     <<<dim3(32, 32),    256, 0, stream>>>(xb, WT, qkvg);
  shift_kernel    <<<dim3(32, 32),    256, 0, stream>>>(qkvg, qrp, krp, vtp);
  retention_kernel<<<dim3(32, 16),    256, 0, stream>>>(qrp, krp, vtp, qkvg, out);
}

// Round 4
// 199.393 us; speedup vs baseline: 1.6141x; 1.6141x over previous
//
#include <hip/hip_runtime.h>

typedef unsigned short u16;
typedef __attribute__((ext_vector_type(8))) __bf16 bf16x8;
typedef __attribute__((ext_vector_type(4))) float f32x4;

#define B_SZ   2
#define S_LEN  2048
#define E_DIM  1024
#define NHEAD  16
#define HD     64
#define KDIM   1024
#define NOUT   4096   // q|k|v|g concatenated

__device__ __forceinline__ float bf2f(u16 u){
  union { unsigned int i; float f; } c; c.i = ((unsigned int)u) << 16; return c.f;
}
__device__ __forceinline__ u16 f2bf(float f){
  union { float f; unsigned int i; } c; c.f = f;
  return (u16)((c.i + 0x7FFFu + ((c.i >> 16) & 1u)) >> 16);
}
__device__ __forceinline__ u16 f2bf_fast(float f){  // round-half-up, 2 ops
  union { float f; unsigned int i; } c; c.f = f;
  return (u16)((c.i + 0x8000u) >> 16);
}
__device__ __forceinline__ void gl2lds16(const void* g, void* l){
  __builtin_amdgcn_global_load_lds((const __attribute__((address_space(1))) void*)g,
                                   (__attribute__((address_space(3))) void*)l, 16, 0, 0);
}

// ---------------- cast x: fp32 -> bf16, tile-swizzled (cb ^= row&7 within 64-col tiles) ----------------
__global__ __launch_bounds__(256) void castx_kernel(const float* __restrict__ x, u16* __restrict__ xb){
  size_t flat = ((size_t)blockIdx.x * 256 + threadIdx.x) * 16;
  int m7 = (int)((flat >> 10) & 7);
  int cb = (int)((flat >> 3) & 7);         // even (16-aligned)
  size_t tile = flat & ~(size_t)63;
  float f[16];
  #pragma unroll
  for (int c = 0; c < 4; c++) *(float4*)&f[c * 4] = *(const float4*)&x[flat + c * 4];
  u16 o[16];
  #pragma unroll
  for (int i = 0; i < 16; i++) o[i] = f2bf(f[i]);
  *(uint4*)&xb[tile + ((cb ^ m7) * 8)]       = *(uint4*)&o[0];
  *(uint4*)&xb[tile + (((cb + 1) ^ m7) * 8)] = *(uint4*)&o[8];
}

// ---------------- W transpose + cast: WT[z*1024 + n][k] = bf16(W_z[k][n]), swizzled ----------------
__global__ __launch_bounds__(256) void wtrans_kernel(const float* __restrict__ Wq, const float* __restrict__ Wk,
                                                     const float* __restrict__ Wv, const float* __restrict__ Wg,
                                                     u16* __restrict__ WT){
  const float* Ws[4] = {Wq, Wk, Wv, Wg};
  const float* W = Ws[blockIdx.z];
  int n0 = blockIdx.x * 64, k0 = blockIdx.y * 64;
  __shared__ u16 tile[64][66];
  int t = threadIdx.x;
  int r = t >> 2, cg = (t & 3) * 16;
  const float* src = W + (size_t)(k0 + r) * E_DIM + n0 + cg;
  float f[16];
  #pragma unroll
  for (int c = 0; c < 4; c++) *(float4*)&f[c * 4] = *(const float4*)&src[c * 4];
  #pragma unroll
  for (int i = 0; i < 16; i++) tile[r][cg + i] = f2bf(f[i]);
  __syncthreads();
  u16 ov[16];
  #pragma unroll
  for (int i = 0; i < 16; i++) ov[i] = tile[cg + i][r];    // (n=n0+r, k=k0+cg+i)
  int n7 = r & 7, cb = cg >> 3;
  u16* dst = WT + (size_t)(blockIdx.z * E_DIM + n0 + r) * KDIM + k0;
  *(uint4*)&dst[(cb ^ n7) * 8]       = *(uint4*)&ov[0];
  *(uint4*)&dst[((cb + 1) ^ n7) * 8] = *(uint4*)&ov[8];
}

// ---------------- fused QKVG GEMM: C[4096 tok][4096] = xb @ [Wq|Wk|Wv|Wg] (bf16, swizzled LDS) ----------------
__global__ __launch_bounds__(256) void gemm_kernel(const u16* __restrict__ A, const u16* __restrict__ Bt,
                                                   u16* __restrict__ C){
  __shared__ __align__(16) u16 As[128 * 64];
  __shared__ __align__(16) u16 Bs[128 * 64];
  int m0 = blockIdx.y * 128, n0 = blockIdx.x * 128;
  int t = threadIdx.x;
  int wave = t >> 6, lane = t & 63;
  int l15 = lane & 15, quad = lane >> 4, h8 = lane & 7;
  int r0 = (wave & 1) * 64, c0 = (wave >> 1) * 64;
  f32x4 acc[4][4];
  #pragma unroll
  for (int i = 0; i < 4; i++)
    #pragma unroll
    for (int j = 0; j < 4; j++) acc[i][j] = (f32x4){0.f, 0.f, 0.f, 0.f};

  for (int k0 = 0; k0 < KDIM; k0 += 64){
    __syncthreads();
    #pragma unroll
    for (int c = 0; c < 4; c++){
      int L = c * 256 + t;
      gl2lds16(A + (size_t)(m0 + (L >> 3)) * KDIM + k0 + (L & 7) * 8, &As[L * 8]);
    }
    #pragma unroll
    for (int c = 0; c < 4; c++){
      int L = c * 256 + t;
      gl2lds16(Bt + (size_t)(n0 + (L >> 3)) * KDIM + k0 + (L & 7) * 8, &Bs[L * 8]);
    }
    __syncthreads();
    #pragma unroll
    for (int kk = 0; kk < 2; kk++){
      bf16x8 a[4], b[4];
      #pragma unroll
      for (int i = 0; i < 4; i++) a[i] = *(const bf16x8*)&As[(r0 + i * 16 + l15) * 64 + ((kk * 4 + quad) ^ h8) * 8];
      #pragma unroll
      for (int j = 0; j < 4; j++) b[j] = *(const bf16x8*)&Bs[(c0 + j * 16 + l15) * 64 + ((kk * 4 + quad) ^ h8) * 8];
      #pragma unroll
      for (int i = 0; i < 4; i++)
        #pragma unroll
        for (int j = 0; j < 4; j++)
          acc[i][j] = __builtin_amdgcn_mfma_f32_16x16x32_bf16(a[i], b[j], acc[i][j], 0, 0, 0);
    }
  }
  #pragma unroll
  for (int i = 0; i < 4; i++){
    int row = m0 + r0 + i * 16 + quad * 4;
    #pragma unroll
    for (int j = 0; j < 4; j++){
      int col = n0 + c0 + j * 16 + l15;
      #pragma unroll
      for (int r = 0; r < 4; r++)
        C[(size_t)(row + r) * NOUT + col] = f2bf(acc[i][j][r]);
    }
  }
}

// ---------------- rotary shift + head-major transpose ----------------
// qr: (B*H, S, D) PLAIN ; kr: (B*H, S, D) swizzled ; vt: (B*H, D, S) swizzled ; k folds E^-0.5.
__global__ __launch_bounds__(256) void shift_kernel(const u16* __restrict__ qkvg,
                                                    u16* __restrict__ qr, u16* __restrict__ kr,
                                                    u16* __restrict__ vt){
  int sb = blockIdx.x, bh = blockIdx.y;
  int s0 = sb * 64;
  int t = threadIdx.x;
  int sl = t >> 2, dg = (t & 3) * 16;
  int s = s0 + sl;
  int h = bh & 15;
  size_t token = (size_t)(bh >> 4) * S_LEN + s;
  size_t base = token * NOUT + h * HD + dg;
  u16 qv[16], kv[16], vv[16];
  *(uint4*)&qv[0] = *(const uint4*)&qkvg[base];
  *(uint4*)&qv[8] = *(const uint4*)&qkvg[base + 8];
  *(uint4*)&kv[0] = *(const uint4*)&qkvg[base + 1024];
  *(uint4*)&kv[8] = *(const uint4*)&qkvg[base + 1024 + 8];
  *(uint4*)&vv[0] = *(const uint4*)&qkvg[base + 2048];
  *(uint4*)&vv[8] = *(const uint4*)&qkvg[base + 2048 + 8];
  u16 qo[16], ko[16];
  #pragma unroll
  for (int i = 0; i < 8; i++){
    int dd = dg + 2 * i;
    float a = exp2f(-(float)(dd >> 1) * (13.287712379549449f / 31.0f));
    float ang = (float)s * a;
    float sn = sinf(ang), cs = cosf(ang);
    float qe = bf2f(qv[2 * i]), qd = bf2f(qv[2 * i + 1]);
    qo[2 * i]     = f2bf(qe * cs - qd * sn);
    qo[2 * i + 1] = f2bf(qd * cs + qe * sn);
    float ke = bf2f(kv[2 * i]) * 0.03125f, kd = bf2f(kv[2 * i + 1]) * 0.03125f;
    ko[2 * i]     = f2bf(ke * cs - kd * sn);
    ko[2 * i + 1] = f2bf(kd * cs + ke * sn);
  }
  size_t dsto = ((size_t)bh * S_LEN + s) * HD;
  *(uint4*)&qr[dsto + dg]     = *(uint4*)&qo[0];
  *(uint4*)&qr[dsto + dg + 8] = *(uint4*)&qo[8];
  int s7 = s & 7, cbk = dg >> 3;
  *(uint4*)&kr[dsto + ((cbk ^ s7) * 8)]       = *(uint4*)&ko[0];
  *(uint4*)&kr[dsto + (((cbk + 1) ^ s7) * 8)] = *(uint4*)&ko[8];
  // v transpose via LDS
  __shared__ u16 vs[64][66];
  #pragma unroll
  for (int i = 0; i < 16; i++) vs[sl][dg + i] = vv[i];
  __syncthreads();
  int d = t >> 2, jg = (t & 3) * 16;
  u16 ov[16];
  #pragma unroll
  for (int i = 0; i < 16; i++) ov[i] = vs[jg + i][d];   // (d, s0+jg+i)
  int d7 = d & 7, cbv = jg >> 3;
  size_t vrow = ((size_t)bh * HD + d) * S_LEN + s0;
  *(uint4*)&vt[vrow + ((cbv ^ d7) * 8)]       = *(uint4*)&ov[0];
  *(uint4*)&vt[vrow + (((cbv + 1) ^ d7) * 8)] = *(uint4*)&ov[8];
}

// ---------------- fused retention: 128-row Q tile, separable mask, swizzled K/V ----------------
// __launch_bounds__(256,2): VGPR cap 256/wave -> NO SPILLS. (256,4) capped at 128 and spilled
// ~200 MB of scratch per dispatch (round-3 post-mortem). Grid is 2 blocks/CU anyway.
__global__ __launch_bounds__(256, 2) void retention_kernel(const u16* __restrict__ qr, const u16* __restrict__ kr,
                                                           const u16* __restrict__ vt, const u16* __restrict__ qkvg,
                                                           float* __restrict__ out){
  int bh = blockIdx.x;
  int qb = 15 - (int)blockIdx.y;          // big-first dispatch
  int b = bh >> 4, h = bh & 15;
  int q0 = qb * 128;
  __shared__ __align__(16) u16 Ks[64 * 64];
  __shared__ __align__(16) u16 Vs[64 * 64];
  __shared__ __align__(16) u16 Ps[128 * 72];   // stride 72: bank-floor reads, 2-way (free) writes
  int t = threadIdx.x, wave = t >> 6, lane = t & 63;
  int l15 = lane & 15, quad = lane >> 4, h8 = lane & 7;

  float decay = log1pf(-exp2f(-5.0f - (float)h));   // ln(gamma_h) < 0
  float negd = -decay;
  float estep = __expf(64.0f * negd);               // growth of row factor per 64-step

  int qsE[2]; int rowbase[2];
  #pragma unroll
  for (int e = 0; e < 2; e++){ rowbase[e] = wave * 32 + e * 16; qsE[e] = q0 + rowbase[e]; }

  // Q fragments direct from global (plain layout)
  bf16x8 aqa[2], aqb[2];
  #pragma unroll
  for (int e = 0; e < 2; e++){
    size_t qrow = ((size_t)bh * S_LEN + qsE[e] + l15) * HD;
    aqa[e] = *(const bf16x8*)&qr[qrow + quad * 8];
    aqb[e] = *(const bf16x8*)&qr[qrow + 32 + quad * 8];
  }

  // hoisted column factor: cf[ct] = exp((j-k0)*|d|), j-k0 = ct*16+l15
  float cf[4];
  #pragma unroll
  for (int ct = 0; ct < 4; ct++) cf[ct] = __expf((float)(ct * 16 + l15) * negd);

  float em1d = expm1f(decay);
  float win_f = 18.0f / negd;
  int win_i = (win_f > 2.1e9f) ? 0x7f000000 : (int)win_f;
  int jmin = q0 - win_i;
  int kb_start = jmin > 0 ? (jmin >> 6) : 0;
  int k0s = kb_start * 64;
  int qi[2][4]; float rf[2][4];
  #pragma unroll
  for (int e = 0; e < 2; e++)
    #pragma unroll
    for (int r = 0; r < 4; r++){
      qi[e][r] = qsE[e] + quad * 4 + r;
      float rowsum = expm1f((float)(qi[e][r] + 1) * decay) / em1d;
      float rinv = rsqrtf(rowsum);
      rf[e][r] = __expf((float)(qi[e][r] - k0s) * decay) * rinv;   // decays toward k0s
    }

  f32x4 o[2][4];
  #pragma unroll
  for (int e = 0; e < 2; e++)
    #pragma unroll
    for (int dt = 0; dt < 4; dt++) o[e][dt] = (f32x4){0.f, 0.f, 0.f, 0.f};
  float babs[2][4] = {{0.f,0.f,0.f,0.f},{0.f,0.f,0.f,0.f}};

  const u16* krbh = kr + (size_t)bh * S_LEN * HD;
  const u16* vtbh = vt + (size_t)bh * HD * S_LEN;
  int kbend = 2 * qb + 1;

  for (int kb = kb_start; kb <= kbend; kb++){
    int k0 = kb * 64;
    __syncthreads();
    #pragma unroll
    for (int c = 0; c < 2; c++){
      int L = c * 256 + t;
      gl2lds16(krbh + (size_t)(k0) * HD + L * 8, &Ks[L * 8]);
    }
    #pragma unroll
    for (int c = 0; c < 2; c++){
      int L = c * 256 + t;
      gl2lds16(vtbh + (size_t)(L >> 3) * S_LEN + k0 + (L & 7) * 8, &Vs[L * 8]);
    }
    __syncthreads();

    // K b-frags (swizzled rows)
    bf16x8 bk0[4], bk1[4];
    #pragma unroll
    for (int ct = 0; ct < 4; ct++){
      int rw = (ct * 16 + l15) * 64;
      bk0[ct] = *(const bf16x8*)&Ks[rw + ((quad ^ h8) * 8)];
      bk1[ct] = *(const bf16x8*)&Ks[rw + (((quad + 4) ^ h8) * 8)];
    }
    #pragma unroll
    for (int e = 0; e < 2; e++){
      int qs = qsE[e];
      if (k0 <= qs + 15 && k0 + 63 >= qs - win_i){
        bool diag = (k0 + 64 > qs);
        #pragma unroll
        for (int ct = 0; ct < 4; ct++){
          f32x4 z = (f32x4){0.f, 0.f, 0.f, 0.f};
          z = __builtin_amdgcn_mfma_f32_16x16x32_bf16(aqa[e], bk0[ct], z, 0, 0, 0);
          z = __builtin_amdgcn_mfma_f32_16x16x32_bf16(aqb[e], bk1[ct], z, 0, 0, 0);
          int j = k0 + ct * 16 + l15;
          #pragma unroll
          for (int r = 0; r < 4; r++){
            float p = z[r] * (rf[e][r] * cf[ct]);
            if (diag && j > qi[e][r]) p = 0.f;
            babs[e][r] += fabsf(p);
            Ps[(rowbase[e] + quad * 4 + r) * 72 + ct * 16 + l15] = f2bf_fast(p);
          }
        }
      }
    }
    // V b-frags (swizzled rows) + PV
    #pragma unroll
    for (int e = 0; e < 2; e++){
      int qs = qsE[e];
      if (k0 <= qs + 15 && k0 + 63 >= qs - win_i){
        bf16x8 ap0 = *(const bf16x8*)&Ps[(rowbase[e] + l15) * 72 + quad * 8];
        bf16x8 ap1 = *(const bf16x8*)&Ps[(rowbase[e] + l15) * 72 + 32 + quad * 8];
        #pragma unroll
        for (int dt = 0; dt < 4; dt++){
          int rw = (dt * 16 + l15) * 64;
          bf16x8 bv0 = *(const bf16x8*)&Vs[rw + ((quad ^ h8) * 8)];
          bf16x8 bv1 = *(const bf16x8*)&Vs[rw + (((quad + 4) ^ h8) * 8)];
          o[e][dt] = __builtin_amdgcn_mfma_f32_16x16x32_bf16(ap0, bv0, o[e][dt], 0, 0, 0);
          o[e][dt] = __builtin_amdgcn_mfma_f32_16x16x32_bf16(ap1, bv1, o[e][dt], 0, 0, 0);
        }
      }
    }
    // advance row factors (k0 += 64 => rf *= exp(64*|d|))
    #pragma unroll
    for (int e = 0; e < 2; e++)
      #pragma unroll
      for (int r = 0; r < 4; r++) rf[e][r] *= estep;
  }

  // ---- epilogue: denom clip, RMS over D, SiLU(g) gate ----
  #pragma unroll
  for (int e = 0; e < 2; e++){
    float dinv[4];
    #pragma unroll
    for (int r = 0; r < 4; r++){
      float v = babs[e][r];
      v += __shfl_xor(v, 1); v += __shfl_xor(v, 2);
      v += __shfl_xor(v, 4); v += __shfl_xor(v, 8);
      dinv[r] = 1.0f / fminf(fmaxf(v, 1.0f), 50000.0f);
    }
    float ssq[4] = {0.f, 0.f, 0.f, 0.f};
    #pragma unroll
    for (int dt = 0; dt < 4; dt++)
      #pragma unroll
      for (int r = 0; r < 4; r++){
        float v = o[e][dt][r] * dinv[r];
        o[e][dt][r] = v;
        ssq[r] += v * v;
      }
    #pragma unroll
    for (int r = 0; r < 4; r++){
      float v = ssq[r];
      v += __shfl_xor(v, 1); v += __shfl_xor(v, 2);
      v += __shfl_xor(v, 4); v += __shfl_xor(v, 8);
      ssq[r] = rsqrtf(v * (1.0f / 64.0f) + 1e-6f);
    }
    #pragma unroll
    for (int r = 0; r < 4; r++){
      int s = qi[e][r];
      size_t gbase = ((size_t)b * S_LEN + s) * NOUT + 3072 + h * HD;
      size_t obase = ((size_t)b * S_LEN + s) * E_DIM + h * HD;
      #pragma unroll
      for (int dt = 0; dt < 4; dt++){
        int d = dt * 16 + l15;
        float gv = bf2f(qkvg[gbase + d]);
        float sg = gv / (1.0f + __expf(-gv));
        out[obase + d] = o[e][dt][r] * ssq[r] * sg;
      }
    }
  }
}

extern "C" void kernel_launch(void* const* d_in, const int* in_sizes, int n_in,
                              void* d_out, int out_size, void* d_ws, size_t ws_size,
                              hipStream_t stream){
  const float* x  = (const float*)d_in[0];
  const float* Wq = (const float*)d_in[1];
  const float* Wk = (const float*)d_in[2];
  const float* Wv = (const float*)d_in[3];
  const float* Wg = (const float*)d_in[4];
  float* out = (float*)d_out;
  char* ws = (char*)d_ws;
  // ws layout: xb->qr overlay [0,8M) | WT->vt overlay [8,16M) | qkvg [16,48M) | kr [48,56M)
  u16* xb   = (u16*)(ws);
  u16* WT   = (u16*)(ws + (8ull  << 20));
  u16* qkvg = (u16*)(ws + (16ull << 20));
  u16* qrp  = (u16*)(ws);
  u16* vtp  = (u16*)(ws + (8ull  << 20));
  u16* krp  = (u16*)(ws + (48ull << 20));

  castx_kernel    <<<dim3(1024),      256, 0, stream>>>(x, xb);
  wtrans_kernel   <<<dim3(16, 16, 4), 256, 0, stream>>>(Wq, Wk, Wv, Wg, WT);
  gemm_kernel     <<<dim3(32, 32),    256, 0, stream>>>(xb, WT, qkvg);
  shift_kernel    <<<dim3(32, 32),    256, 0, stream>>>(qkvg, qrp, krp, vtp);
  retention_kernel<<<dim3(32, 16),    256, 0, stream>>>(qrp, krp, vtp, qkvg, out);
}

// Round 5
// 195.114 us; speedup vs baseline: 1.6494x; 1.0219x over previous
//
#include <hip/hip_runtime.h>

typedef unsigned short u16;
typedef unsigned int u32;
typedef __attribute__((ext_vector_type(8))) __bf16 bf16x8;
typedef __attribute__((ext_vector_type(4))) float f32x4;

#define B_SZ   2
#define S_LEN  2048
#define E_DIM  1024
#define NHEAD  16
#define HD     64
#define KDIM   1024
#define NOUT   4096   // q|k|v|g concatenated

__device__ __forceinline__ float bf2f(u16 u){
  union { u32 i; float f; } c; c.i = ((u32)u) << 16; return c.f;
}
__device__ __forceinline__ u16 f2bf(float f){
  union { float f; u32 i; } c; c.f = f;
  return (u16)((c.i + 0x7FFFu + ((c.i >> 16) & 1u)) >> 16);
}
__device__ __forceinline__ u16 f2bf_fast(float f){  // round-half-up, 2 ops
  union { float f; u32 i; } c; c.f = f;
  return (u16)((c.i + 0x8000u) >> 16);
}
__device__ __forceinline__ void gl2lds16(const void* g, void* l){
  __builtin_amdgcn_global_load_lds((const __attribute__((address_space(1))) void*)g,
                                   (__attribute__((address_space(3))) void*)l, 16, 0, 0);
}

// ---------------- cast x: fp32 -> bf16, tile-swizzled (cb ^= row&7 within 64-col tiles) ----------------
__global__ __launch_bounds__(256) void castx_kernel(const float* __restrict__ x, u16* __restrict__ xb){
  size_t flat = ((size_t)blockIdx.x * 256 + threadIdx.x) * 16;
  int m7 = (int)((flat >> 10) & 7);
  int cb = (int)((flat >> 3) & 7);
  size_t tile = flat & ~(size_t)63;
  float f[16];
  #pragma unroll
  for (int c = 0; c < 4; c++) *(float4*)&f[c * 4] = *(const float4*)&x[flat + c * 4];
  u16 o[16];
  #pragma unroll
  for (int i = 0; i < 16; i++) o[i] = f2bf(f[i]);
  *(uint4*)&xb[tile + ((cb ^ m7) * 8)]       = *(uint4*)&o[0];
  *(uint4*)&xb[tile + (((cb + 1) ^ m7) * 8)] = *(uint4*)&o[8];
}

// ---------------- W transpose + cast: WT[z*1024 + n][k] = bf16(W_z[k][n]), swizzled ----------------
__global__ __launch_bounds__(256) void wtrans_kernel(const float* __restrict__ Wq, const float* __restrict__ Wk,
                                                     const float* __restrict__ Wv, const float* __restrict__ Wg,
                                                     u16* __restrict__ WT){
  const float* Ws[4] = {Wq, Wk, Wv, Wg};
  const float* W = Ws[blockIdx.z];
  int n0 = blockIdx.x * 64, k0 = blockIdx.y * 64;
  __shared__ u16 tile[64][66];
  int t = threadIdx.x;
  int r = t >> 2, cg = (t & 3) * 16;
  const float* src = W + (size_t)(k0 + r) * E_DIM + n0 + cg;
  float f[16];
  #pragma unroll
  for (int c = 0; c < 4; c++) *(float4*)&f[c * 4] = *(const float4*)&src[c * 4];
  #pragma unroll
  for (int i = 0; i < 16; i++) tile[r][cg + i] = f2bf(f[i]);
  __syncthreads();
  u16 ov[16];
  #pragma unroll
  for (int i = 0; i < 16; i++) ov[i] = tile[cg + i][r];
  int n7 = r & 7, cb = cg >> 3;
  u16* dst = WT + (size_t)(blockIdx.z * E_DIM + n0 + r) * KDIM + k0;
  *(uint4*)&dst[(cb ^ n7) * 8]       = *(uint4*)&ov[0];
  *(uint4*)&dst[((cb + 1) ^ n7) * 8] = *(uint4*)&ov[8];
}

// ---------------- fused QKVG GEMM (bf16, swizzled LDS) ----------------
__global__ __launch_bounds__(256) void gemm_kernel(const u16* __restrict__ A, const u16* __restrict__ Bt,
                                                   u16* __restrict__ C){
  __shared__ __align__(16) u16 As[128 * 64];
  __shared__ __align__(16) u16 Bs[128 * 64];
  int m0 = blockIdx.y * 128, n0 = blockIdx.x * 128;
  int t = threadIdx.x;
  int wave = t >> 6, lane = t & 63;
  int l15 = lane & 15, quad = lane >> 4, h8 = lane & 7;
  int r0 = (wave & 1) * 64, c0 = (wave >> 1) * 64;
  f32x4 acc[4][4];
  #pragma unroll
  for (int i = 0; i < 4; i++)
    #pragma unroll
    for (int j = 0; j < 4; j++) acc[i][j] = (f32x4){0.f, 0.f, 0.f, 0.f};

  for (int k0 = 0; k0 < KDIM; k0 += 64){
    __syncthreads();
    #pragma unroll
    for (int c = 0; c < 4; c++){
      int L = c * 256 + t;
      gl2lds16(A + (size_t)(m0 + (L >> 3)) * KDIM + k0 + (L & 7) * 8, &As[L * 8]);
    }
    #pragma unroll
    for (int c = 0; c < 4; c++){
      int L = c * 256 + t;
      gl2lds16(Bt + (size_t)(n0 + (L >> 3)) * KDIM + k0 + (L & 7) * 8, &Bs[L * 8]);
    }
    __syncthreads();
    #pragma unroll
    for (int kk = 0; kk < 2; kk++){
      bf16x8 a[4], b[4];
      #pragma unroll
      for (int i = 0; i < 4; i++) a[i] = *(const bf16x8*)&As[(r0 + i * 16 + l15) * 64 + ((kk * 4 + quad) ^ h8) * 8];
      #pragma unroll
      for (int j = 0; j < 4; j++) b[j] = *(const bf16x8*)&Bs[(c0 + j * 16 + l15) * 64 + ((kk * 4 + quad) ^ h8) * 8];
      #pragma unroll
      for (int i = 0; i < 4; i++)
        #pragma unroll
        for (int j = 0; j < 4; j++)
          acc[i][j] = __builtin_amdgcn_mfma_f32_16x16x32_bf16(a[i], b[j], acc[i][j], 0, 0, 0);
    }
  }
  #pragma unroll
  for (int i = 0; i < 4; i++){
    int row = m0 + r0 + i * 16 + quad * 4;
    #pragma unroll
    for (int j = 0; j < 4; j++){
      int col = n0 + c0 + j * 16 + l15;
      #pragma unroll
      for (int r = 0; r < 4; r++)
        C[(size_t)(row + r) * NOUT + col] = f2bf(acc[i][j][r]);
    }
  }
}

// ---------------- rotary shift + head-major transpose + g-compaction ----------------
// qr: (B*H,S,D) plain ; kr: (B*H,S,D) swizzled ; vt: (B*H,D,S) swizzled ; gc: (B,S,E) compacted g.
__global__ __launch_bounds__(256) void shift_kernel(const u16* __restrict__ qkvg,
                                                    u16* __restrict__ qr, u16* __restrict__ kr,
                                                    u16* __restrict__ vt, u16* __restrict__ gc){
  int sb = blockIdx.x, bh = blockIdx.y;
  int s0 = sb * 64;
  int t = threadIdx.x;
  int sl = t >> 2, dg = (t & 3) * 16;
  int s = s0 + sl;
  int h = bh & 15;
  size_t token = (size_t)(bh >> 4) * S_LEN + s;
  size_t base = token * NOUT + h * HD + dg;
  u16 qv[16], kv[16], vv[16], gv[16];
  *(uint4*)&qv[0] = *(const uint4*)&qkvg[base];
  *(uint4*)&qv[8] = *(const uint4*)&qkvg[base + 8];
  *(uint4*)&kv[0] = *(const uint4*)&qkvg[base + 1024];
  *(uint4*)&kv[8] = *(const uint4*)&qkvg[base + 1024 + 8];
  *(uint4*)&vv[0] = *(const uint4*)&qkvg[base + 2048];
  *(uint4*)&vv[8] = *(const uint4*)&qkvg[base + 2048 + 8];
  *(uint4*)&gv[0] = *(const uint4*)&qkvg[base + 3072];
  *(uint4*)&gv[8] = *(const uint4*)&qkvg[base + 3072 + 8];
  // g compaction (so qkvg region is dead after this kernel -> partials overlay it)
  size_t gdst = token * E_DIM + h * HD + dg;
  *(uint4*)&gc[gdst]     = *(uint4*)&gv[0];
  *(uint4*)&gc[gdst + 8] = *(uint4*)&gv[8];
  u16 qo[16], ko[16];
  #pragma unroll
  for (int i = 0; i < 8; i++){
    int dd = dg + 2 * i;
    float a = exp2f(-(float)(dd >> 1) * (13.287712379549449f / 31.0f));
    float ang = (float)s * a;
    float sn = sinf(ang), cs = cosf(ang);
    float qe = bf2f(qv[2 * i]), qd = bf2f(qv[2 * i + 1]);
    qo[2 * i]     = f2bf(qe * cs - qd * sn);
    qo[2 * i + 1] = f2bf(qd * cs + qe * sn);
    float ke = bf2f(kv[2 * i]) * 0.03125f, kd = bf2f(kv[2 * i + 1]) * 0.03125f;
    ko[2 * i]     = f2bf(ke * cs - kd * sn);
    ko[2 * i + 1] = f2bf(kd * cs + ke * sn);
  }
  size_t dsto = ((size_t)bh * S_LEN + s) * HD;
  *(uint4*)&qr[dsto + dg]     = *(uint4*)&qo[0];
  *(uint4*)&qr[dsto + dg + 8] = *(uint4*)&qo[8];
  int s7 = s & 7, cbk = dg >> 3;
  *(uint4*)&kr[dsto + ((cbk ^ s7) * 8)]       = *(uint4*)&ko[0];
  *(uint4*)&kr[dsto + (((cbk + 1) ^ s7) * 8)] = *(uint4*)&ko[8];
  __shared__ u16 vs[64][66];
  #pragma unroll
  for (int i = 0; i < 16; i++) vs[sl][dg + i] = vv[i];
  __syncthreads();
  int d = t >> 2, jg = (t & 3) * 16;
  u16 ov[16];
  #pragma unroll
  for (int i = 0; i < 16; i++) ov[i] = vs[jg + i][d];
  int d7 = d & 7, cbv = jg >> 3;
  size_t vrow = ((size_t)bh * HD + d) * S_LEN + s0;
  *(uint4*)&vt[vrow + ((cbv ^ d7) * 8)]       = *(uint4*)&ov[0];
  *(uint4*)&vt[vrow + (((cbv + 1) ^ d7) * 8)] = *(uint4*)&ov[8];
}

// ---------------- retention (transpose world): S^T = K Q^T, O^T = V^T P^T ----------------
// kb-range split across blockIdx.z in {0,1}: z=0 -> kb [0,qb], z=1 -> kb [qb+1, 2qb+1] (64-col tiles,
// equal halves). Each block writes an fp32 partial O^T + partial babs; combine_kernel finishes.
// C-layout in transpose world: lane n=l15 carries the TOKEN index i -> rf per-lane scalar, packed b64
// P-stores, per-lane babs accumulation, float4 partial stores.
__global__ __launch_bounds__(256, 2) void retention_kernel(const u16* __restrict__ qr, const u16* __restrict__ kr,
                                                           const u16* __restrict__ vt,
                                                           float* __restrict__ pO, float* __restrict__ pBa){
  int bh = blockIdx.x;
  int qb = 15 - (int)blockIdx.y;          // big-first dispatch
  int z  = blockIdx.z;
  int h = bh & 15;
  int q0 = qb * 128;
  __shared__ __align__(16) u16 Ks[64 * 64];
  __shared__ __align__(16) u16 Vs[64 * 64];
  __shared__ __align__(16) u16 Ps[128 * 72];
  int t = threadIdx.x, wave = t >> 6, lane = t & 63;
  int l15 = lane & 15, quad = lane >> 4, h8 = lane & 7;

  float decay = log1pf(-exp2f(-5.0f - (float)h));   // ln(gamma_h) < 0
  float negd = -decay;
  float estep = __expf(64.0f * negd);

  int qsE[2], rowb[2];
  #pragma unroll
  for (int e = 0; e < 2; e++){ rowb[e] = wave * 32 + e * 16; qsE[e] = q0 + rowb[e]; }

  // Q B-frags (n=i=l15, k=d=quad*8.. ; plain layout)
  bf16x8 qB[2][2];
  #pragma unroll
  for (int e = 0; e < 2; e++){
    size_t qrow = ((size_t)bh * S_LEN + qsE[e] + l15) * HD;
    qB[e][0] = *(const bf16x8*)&qr[qrow + quad * 8];
    qB[e][1] = *(const bf16x8*)&qr[qrow + 32 + quad * 8];
  }

  // window + kb range for this z-half
  float win_f = 18.0f / negd;
  int win_i = (win_f > 2.1e9f) ? 0x7f000000 : (int)win_f;
  int z_lo = z ? (qb + 1) : 0;
  int z_hi = z ? (2 * qb + 1) : qb;
  int kb_lo = z_lo;
  {
    int jmin = q0 - win_i;
    if (jmin > z_lo * 64){ int wlo = jmin >> 6; kb_lo = wlo > z_lo ? wlo : z_lo; }
  }
  int k0s = kb_lo * 64;

  // per-strip per-lane row factor rf = exp((i-k0s)*decay) * rinv_i  (i = qs + l15)
  float em1d = expm1f(decay);
  float rfE[2]; int iE[2];
  #pragma unroll
  for (int e = 0; e < 2; e++){
    int i = qsE[e] + l15;
    iE[e] = i;
    float rowsum = expm1f((float)(i + 1) * decay) / em1d;
    rfE[e] = __expf((float)(i - k0s) * decay) * rsqrtf(rowsum);
  }
  // column factor: cf_j = exp(negd*(j-k0)); j-k0 = ct*16 + quad*4 + r
  float e1 = __expf(negd);
  float c16 = __expf(negd * 16.0f);
  float cbr[4];
  cbr[0] = __expf(negd * (float)(quad * 4));
  cbr[1] = cbr[0] * e1; cbr[2] = cbr[1] * e1; cbr[3] = cbr[2] * e1;

  f32x4 o[2][4];
  #pragma unroll
  for (int e = 0; e < 2; e++)
    #pragma unroll
    for (int dt = 0; dt < 4; dt++) o[e][dt] = (f32x4){0.f, 0.f, 0.f, 0.f};
  float babs[2] = {0.f, 0.f};

  const u16* krbh = kr + (size_t)bh * S_LEN * HD;
  const u16* vtbh = vt + (size_t)bh * HD * S_LEN;

  for (int kb = kb_lo; kb <= z_hi; kb++){
    int k0 = kb * 64;
    __syncthreads();
    #pragma unroll
    for (int c = 0; c < 2; c++){
      int L = c * 256 + t;
      gl2lds16(krbh + (size_t)k0 * HD + L * 8, &Ks[L * 8]);
    }
    #pragma unroll
    for (int c = 0; c < 2; c++){
      int L = c * 256 + t;
      gl2lds16(vtbh + (size_t)(L >> 3) * S_LEN + k0 + (L & 7) * 8, &Vs[L * 8]);
    }
    __syncthreads();

    // K A-frags (m=j=l15-row, swizzled)
    bf16x8 kA0[4], kA1[4];
    #pragma unroll
    for (int ct = 0; ct < 4; ct++){
      int rw = (ct * 16 + l15) * 64;
      kA0[ct] = *(const bf16x8*)&Ks[rw + ((quad ^ h8) * 8)];
      kA1[ct] = *(const bf16x8*)&Ks[rw + (((quad + 4) ^ h8) * 8)];
    }
    #pragma unroll
    for (int e = 0; e < 2; e++){
      int qs = qsE[e];
      if (k0 <= qs + 15 && k0 + 63 >= qs - win_i){
        bool diag = (k0 + 64 > qs);
        float cf[4] = {cbr[0], cbr[1], cbr[2], cbr[3]};
        #pragma unroll
        for (int ct = 0; ct < 4; ct++){
          f32x4 zacc = (f32x4){0.f, 0.f, 0.f, 0.f};
          zacc = __builtin_amdgcn_mfma_f32_16x16x32_bf16(kA0[ct], qB[e][0], zacc, 0, 0, 0);
          zacc = __builtin_amdgcn_mfma_f32_16x16x32_bf16(kA1[ct], qB[e][1], zacc, 0, 0, 0);
          // C: n=i=l15, m=j = k0 + ct*16 + quad*4 + r
          u16 pk[4];
          #pragma unroll
          for (int r = 0; r < 4; r++){
            float p = zacc[r] * (rfE[e] * cf[r]);
            if (diag && (k0 + ct * 16 + quad * 4 + r) > iE[e]) p = 0.f;
            babs[e] += fabsf(p);
            pk[r] = f2bf_fast(p);
            cf[r] *= c16;
          }
          u32 lo = (u32)pk[0] | ((u32)pk[1] << 16);
          u32 hi = (u32)pk[2] | ((u32)pk[3] << 16);
          *(uint2*)&Ps[(rowb[e] + l15) * 72 + ct * 16 + quad * 4] = make_uint2(lo, hi);
        }
      }
    }
    // PV: O^T += V^T P^T
    #pragma unroll
    for (int e = 0; e < 2; e++){
      int qs = qsE[e];
      if (k0 <= qs + 15 && k0 + 63 >= qs - win_i){
        bf16x8 pB0 = *(const bf16x8*)&Ps[(rowb[e] + l15) * 72 + quad * 8];
        bf16x8 pB1 = *(const bf16x8*)&Ps[(rowb[e] + l15) * 72 + 32 + quad * 8];
        #pragma unroll
        for (int dt = 0; dt < 4; dt++){
          int rw = (dt * 16 + l15) * 64;
          bf16x8 vA0 = *(const bf16x8*)&Vs[rw + ((quad ^ h8) * 8)];
          bf16x8 vA1 = *(const bf16x8*)&Vs[rw + (((quad + 4) ^ h8) * 8)];
          o[e][dt] = __builtin_amdgcn_mfma_f32_16x16x32_bf16(vA0, pB0, o[e][dt], 0, 0, 0);
          o[e][dt] = __builtin_amdgcn_mfma_f32_16x16x32_bf16(vA1, pB1, o[e][dt], 0, 0, 0);
        }
      }
    }
    #pragma unroll
    for (int e = 0; e < 2; e++) rfE[e] *= estep;
  }

  // write partials: pO[slot][dt=4][i=128][dsub=16] fp32, pBa[slot][i=128]
  size_t slot = ((size_t)bh * 16 + qb) * 2 + z;
  float* po = pO + slot * (4 * 128 * 16);
  #pragma unroll
  for (int e = 0; e < 2; e++){
    float bsum = babs[e];
    bsum += __shfl_xor(bsum, 16);
    bsum += __shfl_xor(bsum, 32);
    if (quad == 0) pBa[slot * 128 + rowb[e] + l15] = bsum;
    #pragma unroll
    for (int dt = 0; dt < 4; dt++)
      *(float4*)&po[(dt * 128 + rowb[e] + l15) * 16 + quad * 4] = *(float4*)&o[e][dt];
  }
}

// ---------------- combine: sum 2 partials, denom clip, RMS, SiLU(g) gate ----------------
__global__ __launch_bounds__(128) void combine_kernel(const float* __restrict__ pO, const float* __restrict__ pBa,
                                                      const u16* __restrict__ gc, float* __restrict__ out){
  int bh = blockIdx.x, qb = blockIdx.y;
  int b = bh >> 4, h = bh & 15;
  int i = threadIdx.x;                       // token row within tile
  int s = qb * 128 + i;
  size_t s2 = ((size_t)bh * 16 + qb) * 2;
  const float* p0 = pO + s2 * 8192;
  const float* p1 = p0 + 8192;
  float v[64];
  #pragma unroll
  for (int dt = 0; dt < 4; dt++)
    #pragma unroll
    for (int c = 0; c < 4; c++){
      float4 a  = *(const float4*)&p0[(dt * 128 + i) * 16 + c * 4];
      float4 bb = *(const float4*)&p1[(dt * 128 + i) * 16 + c * 4];
      int d = dt * 16 + c * 4;
      v[d + 0] = a.x + bb.x; v[d + 1] = a.y + bb.y;
      v[d + 2] = a.z + bb.z; v[d + 3] = a.w + bb.w;
    }
  float bsum = pBa[s2 * 128 + i] + pBa[(s2 + 1) * 128 + i];
  float dinv = 1.0f / fminf(fmaxf(bsum, 1.0f), 50000.0f);
  float ssq = 0.f;
  #pragma unroll
  for (int d = 0; d < 64; d++){ v[d] *= dinv; ssq += v[d] * v[d]; }
  float rms = rsqrtf(ssq * (1.0f / 64.0f) + 1e-6f);
  size_t gbase = ((size_t)b * S_LEN + s) * E_DIM + h * HD;
  u16 gu[64];
  #pragma unroll
  for (int c = 0; c < 8; c++) *(uint4*)&gu[c * 8] = *(const uint4*)&gc[gbase + c * 8];
  float ov[64];
  #pragma unroll
  for (int d = 0; d < 64; d++){
    float gv = bf2f(gu[d]);
    float sg = gv / (1.0f + __expf(-gv));
    ov[d] = v[d] * rms * sg;
  }
  float* obase = out + ((size_t)b * S_LEN + s) * E_DIM + h * HD;
  #pragma unroll
  for (int c = 0; c < 16; c++) *(float4*)&obase[c * 4] = *(float4*)&ov[c * 4];
}

extern "C" void kernel_launch(void* const* d_in, const int* in_sizes, int n_in,
                              void* d_out, int out_size, void* d_ws, size_t ws_size,
                              hipStream_t stream){
  const float* x  = (const float*)d_in[0];
  const float* Wq = (const float*)d_in[1];
  const float* Wk = (const float*)d_in[2];
  const float* Wv = (const float*)d_in[3];
  const float* Wg = (const float*)d_in[4];
  float* out = (float*)d_out;
  char* ws = (char*)d_ws;
  // ws layout (stream-ordered overlays):
  //   [0,8M):   xb (dead after gemm)   -> qr
  //   [8,16M):  WT (dead after gemm)   -> vt
  //   [16,48M): qkvg (dead after shift; g compacted out) -> pO partials (32MB)
  //   [48,56M): kr
  //   [56,64M): gc (compacted g)
  //   [64,64.5M): pBa (babs partials)
  u16*   xb   = (u16*)(ws);
  u16*   WT   = (u16*)(ws + (8ull  << 20));
  u16*   qkvg = (u16*)(ws + (16ull << 20));
  u16*   qrp  = (u16*)(ws);
  u16*   vtp  = (u16*)(ws + (8ull  << 20));
  float* pO   = (float*)(ws + (16ull << 20));
  u16*   krp  = (u16*)(ws + (48ull << 20));
  u16*   gcp  = (u16*)(ws + (56ull << 20));
  float* pBa  = (float*)(ws + (64ull << 20));

  castx_kernel    <<<dim3(1024),       256, 0, stream>>>(x, xb);
  wtrans_kernel   <<<dim3(16, 16, 4),  256, 0, stream>>>(Wq, Wk, Wv, Wg, WT);
  gemm_kernel     <<<dim3(32, 32),     256, 0, stream>>>(xb, WT, qkvg);
  shift_kernel    <<<dim3(32, 32),     256, 0, stream>>>(qkvg, qrp, krp, vtp, gcp);
  retention_kernel<<<dim3(32, 16, 2),  256, 0, stream>>>(qrp, krp, vtp, pO, pBa);
  combine_kernel  <<<dim3(32, 16),     128, 0, stream>>>(pO, pBa, gcp, out);
}